// Round 6
// baseline (245.759 us; speedup 1.0000x reference)
//
#include <hip/hip_runtime.h>
#include <hip/hip_bf16.h>

// MLPPredictor: score[e] = W2 . relu(W1 @ concat(h[src],h[dst]) + b1) + b2
// SETTLED (R0-R5, hardware-verified): h/W1/b1/W2/b2 = float32, src/dst = int32
// (harness converts int64->int32), out = FLOAT32 (reference output dtype; the
// "bf16" in the harness error label is a hardcoded f-string literal, not a
// dtype indicator — R1-R5's failures were all the bf16-vs-fp32 OUTPUT write).
// MFMA fragment maps (probe-verified on gfx950 in R5, mode 0):
//   A: lane holds A[m=lane&15][k=(lane>>4)*8+j]
//   B: lane holds B[k=(lane>>4)*8+j][n=lane&15]
//   D: lane reg r holds D[row=(lane>>4)*4+r][col=lane&15]
// Core: pre-convert h fp32->bf16 into d_ws (halves gather bytes), stage W1 as
// bf16 in 64KB XOR-swizzled LDS, mfma_f32_16x16x32_bf16, fused relu+dot(w2)
// epilogue, fp32 accumulate, fp32 stores.

typedef __attribute__((ext_vector_type(8))) short short8;   // 8 bf16 = 4 VGPRs
typedef __attribute__((ext_vector_type(4))) float floatx4;  // MFMA acc

constexpr int HF = 128;   // H_FEATS
constexpr int K2 = 256;   // 2*H (concat dim)

__device__ __forceinline__ short8 pack_bf16_8(float4 a, float4 b) {
    union { short8 v; __hip_bfloat16 e[8]; } u;
    u.e[0] = __float2bfloat16(a.x); u.e[1] = __float2bfloat16(a.y);
    u.e[2] = __float2bfloat16(a.z); u.e[3] = __float2bfloat16(a.w);
    u.e[4] = __float2bfloat16(b.x); u.e[5] = __float2bfloat16(b.y);
    u.e[6] = __float2bfloat16(b.z); u.e[7] = __float2bfloat16(b.w);
    return u.v;
}

// ---- pre-pass: h float32 -> bf16 into workspace (~38 MB streamed, ~6 us) ----
__global__ __launch_bounds__(256) void cvt_bf16(const float* __restrict__ src,
                                                unsigned short* __restrict__ dst,
                                                int n8) {
    int i = blockIdx.x * 256 + threadIdx.x;
    if (i < n8) {
        const float4* p = (const float4*)src + (size_t)i * 2;
        *(short8*)(dst + (size_t)i * 8) = pack_bf16_8(p[0], p[1]);
    }
}

// LDS W1: 128 rows x 256 bf16 = 64 KB. Rows are 512 B (bank-aligned); 16B
// chunks are XOR-swizzled by (row&7) -> wave b128 reads spread over all 32
// banks (2 lanes/bank = free, m136).

template <bool HB16>
__global__ __launch_bounds__(256, 2) void mlp_edge(
    const void* __restrict__ hsrc,            // bf16 ws copy or fp32 original
    const int* __restrict__ src,
    const int* __restrict__ dst,
    const float* __restrict__ W1,
    const float* __restrict__ b1,
    const float* __restrict__ W2,
    const float* __restrict__ b2,
    float* __restrict__ out,                  // FLOAT32 output
    const int n_edges,
    const int n_groups)
{
    __shared__ __hip_bfloat16 sW[HF * K2];   // 64 KB

    const int tid = threadIdx.x;

    // ---- stage W1 (fp32) into LDS as bf16, swizzled 16B chunks ----
    {
        const float4* gw = (const float4*)W1;         // 8192 float4
        #pragma unroll
        for (int i = 0; i < 16; ++i) {
            const int c   = tid + i * 256;            // 16B-bf16 chunk id
            const int row = c >> 5;                   // 32 chunks per row
            const int col = (c & 31) ^ (row & 7);     // swizzled chunk-in-row
            float4 va = gw[2 * c], vb = gw[2 * c + 1];
            *(short8*)(&sW[row * K2 + (col << 3)]) = pack_bf16_8(va, vb);
        }
    }
    __syncthreads();

    const int lane = tid & 63;
    const int wave = tid >> 6;
    const int c16  = lane & 15;    // A row / B col / C col within tile
    const int q    = lane >> 4;    // quad
    const int swz  = c16 & 7;      // read swizzle (row&7 == c16&7)
    const int gb   = lane & 48;    // shfl group base

    // ---- epilogue constants (fp32) ----
    float b1f[8], w2f[8];
    #pragma unroll
    for (int t = 0; t < 8; ++t) {
        b1f[t] = b1[t * 16 + c16];
        w2f[t] = W2[t * 16 + c16];
    }
    const float b2f = b2[0];

    const floatx4 vzero = {0.f, 0.f, 0.f, 0.f};

    // ---- grid-stride over 128-edge groups; each wave does 32 edges ----
    for (int g = blockIdx.x; g < n_groups; g += gridDim.x) {
        const int base = g * 128 + wave * 32;

        const int e0 = base + c16;          // subtile-0 A-row edge
        const int e1 = base + 16 + c16;     // subtile-1 A-row edge
        const int s0 = (e0 < n_edges) ? src[e0] : 0;
        const int d0 = (e0 < n_edges) ? dst[e0] : 0;
        const int s1 = (e1 < n_edges) ? src[e1] : 0;
        const int d1 = (e1 < n_edges) ? dst[e1] : 0;

        // A-frags: f in [0,4) = src feats k=f*32+q*8..+8; f in [4,8) = dst
        short8 a0[8], a1[8];
        if (HB16) {
            const unsigned short* hb = (const unsigned short*)hsrc;
            const short8* ps0 = (const short8*)(hb + (size_t)s0 * HF);
            const short8* pd0 = (const short8*)(hb + (size_t)d0 * HF);
            const short8* ps1 = (const short8*)(hb + (size_t)s1 * HF);
            const short8* pd1 = (const short8*)(hb + (size_t)d1 * HF);
            #pragma unroll
            for (int f = 0; f < 4; ++f) {
                a0[f]     = ps0[f * 4 + q];
                a0[f + 4] = pd0[f * 4 + q];
                a1[f]     = ps1[f * 4 + q];
                a1[f + 4] = pd1[f * 4 + q];
            }
        } else {
            const float* hf = (const float*)hsrc;
            const float4* ps0 = (const float4*)(hf + (size_t)s0 * HF);
            const float4* pd0 = (const float4*)(hf + (size_t)d0 * HF);
            const float4* ps1 = (const float4*)(hf + (size_t)s1 * HF);
            const float4* pd1 = (const float4*)(hf + (size_t)d1 * HF);
            #pragma unroll
            for (int f = 0; f < 4; ++f) {
                const int o = f * 8 + q * 2;
                a0[f]     = pack_bf16_8(ps0[o], ps0[o + 1]);
                a0[f + 4] = pack_bf16_8(pd0[o], pd0[o + 1]);
                a1[f]     = pack_bf16_8(ps1[o], ps1[o + 1]);
                a1[f + 4] = pack_bf16_8(pd1[o], pd1[o + 1]);
            }
        }

        floatx4 acc0[8], acc1[8];
        #pragma unroll
        for (int t = 0; t < 8; ++t) { acc0[t] = vzero; acc1[t] = vzero; }

        // K-loop: 8 steps of 32; 8 feature-tiles; B-frag shared by both subtiles
        #pragma unroll
        for (int ks = 0; ks < 8; ++ks) {
            #pragma unroll
            for (int t = 0; t < 8; ++t) {
                const int chunk = (ks * 4 + q) ^ swz;
                const short8 bfr = *(const short8*)(&sW[(t * 16 + c16) * K2 + (chunk << 3)]);
                acc0[t] = __builtin_amdgcn_mfma_f32_16x16x32_bf16(a0[ks], bfr, acc0[t], 0, 0, 0);
                acc1[t] = __builtin_amdgcn_mfma_f32_16x16x32_bf16(a1[ks], bfr, acc1[t], 0, 0, 0);
            }
        }

        // ---- epilogue: relu(z+b1).w2; lane reg r = z[base'+q*4+r][t*16+c16] ----
        float p0[4] = {0.f, 0.f, 0.f, 0.f};
        float p1[4] = {0.f, 0.f, 0.f, 0.f};
        #pragma unroll
        for (int t = 0; t < 8; ++t) {
            #pragma unroll
            for (int r = 0; r < 4; ++r) {
                p0[r] += fmaxf(acc0[t][r] + b1f[t], 0.f) * w2f[t];
                p1[r] += fmaxf(acc1[t][r] + b1f[t], 0.f) * w2f[t];
            }
        }
        // reduce across the 16 feature-lanes of each quad
        #pragma unroll
        for (int off = 8; off >= 1; off >>= 1) {
            #pragma unroll
            for (int r = 0; r < 4; ++r) {
                p0[r] += __shfl(p0[r], gb | (c16 ^ off));
                p1[r] += __shfl(p1[r], gb | (c16 ^ off));
            }
        }
        if (c16 < 4) {
            const float r0 = (c16 == 0) ? p0[0] : (c16 == 1) ? p0[1] : (c16 == 2) ? p0[2] : p0[3];
            const float r1 = (c16 == 0) ? p1[0] : (c16 == 1) ? p1[1] : (c16 == 2) ? p1[2] : p1[3];
            const int eo0 = base + q * 4 + c16;
            const int eo1 = base + 16 + q * 4 + c16;
            if (eo0 < n_edges) out[eo0] = r0 + b2f;   // fp32 store
            if (eo1 < n_edges) out[eo1] = r1 + b2f;   // fp32 store
        }
    }
}

extern "C" void kernel_launch(void* const* d_in, const int* in_sizes, int n_in,
                              void* d_out, int out_size, void* d_ws, size_t ws_size,
                              hipStream_t stream) {
    const float* h   = (const float*)d_in[0];
    const int*   src = (const int*)d_in[1];
    const int*   dst = (const int*)d_in[2];
    const float* W1  = (const float*)d_in[3];
    const float* b1  = (const float*)d_in[4];
    const float* W2  = (const float*)d_in[5];
    const float* b2  = (const float*)d_in[6];
    float* out = (float*)d_out;

    const int n_edges  = in_sizes[1];
    const int n_groups = (n_edges + 127) / 128;
    int grid = 512;                      // 2 blocks/CU (64 KB LDS), persistent
    if (grid > n_groups) grid = n_groups;

    const int    h_elems  = in_sizes[0];
    const size_t hb_bytes = (size_t)h_elems * 2;

    if (ws_size >= hb_bytes && (h_elems & 7) == 0) {
        unsigned short* hb = (unsigned short*)d_ws;
        const int n8 = h_elems / 8;
        cvt_bf16<<<dim3((n8 + 255) / 256), dim3(256), 0, stream>>>(h, hb, n8);
        mlp_edge<true><<<dim3(grid), dim3(256), 0, stream>>>(
            (const void*)hb, src, dst, W1, b1, W2, b2, out, n_edges, n_groups);
    } else {
        mlp_edge<false><<<dim3(grid), dim3(256), 0, stream>>>(
            (const void*)h, src, dst, W1, b1, W2, b2, out, n_edges, n_groups);
    }
}

// Round 7
// 134.102 us; speedup vs baseline: 1.8326x; 1.8326x over previous
//
#include <hip/hip_runtime.h>
#include <hip/hip_bf16.h>

// MLPPredictor: score[e] = W2 . relu(W1 @ concat(h[src],h[dst]) + b1) + b2
// SETTLED (R0-R6): h/W1/b1/W2/b2 = fp32, src/dst = int32, out = fp32.
// R6 (mlp_edge MFMA gather-GEMM) passed at 166 us steady, traffic-bound:
// 468 MB fetch @3.35 TB/s, all pipes <10%, occupancy 21% (64 KB LDS cap).
//
// R7 split: z = W1a@h_s + W1b@h_d  =>  precompute per-node
//   u[v] = W1a @ h[v] + b1   (bf16, ws[0..12.8MB))
//   w[v] = W1b @ h[v]        (bf16, ws[12.8..25.6MB))
// with a small MFMA GEMM (probe-verified fragment maps, R5 mode 0):
//   A: lane holds A[m=lane&15][k=(lane>>4)*8+j]
//   B: lane holds B[k=(lane>>4)*8+j][n=lane&15]
//   D: lane reg r holds D[row=(lane>>4)*4+r][col=lane&15]
// then a pure-gather edge kernel: 16 lanes/edge, 256B coalesced row reads,
// relu+dot(W2) in VALU, float4 stores. No LDS -> full occupancy.

typedef __attribute__((ext_vector_type(8))) short short8;   // 8 bf16
typedef __attribute__((ext_vector_type(4))) float floatx4;  // MFMA acc

constexpr int HF = 128;   // H_FEATS
constexpr int K2 = 256;   // 2*H

union BF8 { short8 v; __hip_bfloat16 e[8]; };

__device__ __forceinline__ short8 pack_bf16_8(float4 a, float4 b) {
    BF8 u;
    u.e[0] = __float2bfloat16(a.x); u.e[1] = __float2bfloat16(a.y);
    u.e[2] = __float2bfloat16(a.z); u.e[3] = __float2bfloat16(a.w);
    u.e[4] = __float2bfloat16(b.x); u.e[5] = __float2bfloat16(b.y);
    u.e[6] = __float2bfloat16(b.z); u.e[7] = __float2bfloat16(b.w);
    return u.v;
}

__device__ __forceinline__ float bf2f(unsigned short s) {
    union { unsigned u; float f; } c; c.u = (unsigned)s << 16; return c.f;
}

// =================== R7 precompute: u/w per-node GEMM ===================
__global__ __launch_bounds__(256, 2) void gemm_uw(
    const float* __restrict__ h,
    const float* __restrict__ W1,
    const float* __restrict__ b1,
    unsigned short* __restrict__ uo,     // [n_nodes][128] bf16 (includes +b1)
    unsigned short* __restrict__ wo,     // [n_nodes][128] bf16
    const int n_nodes,
    const int n_groups)
{
    __shared__ __hip_bfloat16 sW[HF * K2];   // 64 KB, swizzled

    const int tid = threadIdx.x;
    {
        const float4* gw = (const float4*)W1;
        #pragma unroll
        for (int i = 0; i < 16; ++i) {
            const int c = tid + i * 256, row = c >> 5, col = (c & 31) ^ (row & 7);
            *(short8*)(&sW[row * K2 + (col << 3)]) = pack_bf16_8(gw[2 * c], gw[2 * c + 1]);
        }
    }
    __syncthreads();

    const int lane = tid & 63;
    const int wave = tid >> 6;
    const int c16  = lane & 15;
    const int q    = lane >> 4;
    const int swz  = c16 & 7;

    float b1f[8];
    #pragma unroll
    for (int t = 0; t < 8; ++t) b1f[t] = b1[t * 16 + c16];

    const floatx4 vzero = {0.f, 0.f, 0.f, 0.f};

    for (int g = blockIdx.x; g < n_groups; g += gridDim.x) {
        const int nbase = g * 128 + wave * 32;
        const int n0 = nbase + c16;          // subtile-0 A-row node
        const int n1 = nbase + 16 + c16;     // subtile-1 A-row node
        const int s0 = (n0 < n_nodes) ? n0 : 0;
        const int s1 = (n1 < n_nodes) ? n1 : 0;

        // A-frags (K=128 of h row, fp32 -> bf16): frag f covers k=f*32+q*8..+8
        const float4* p0 = (const float4*)(h + (size_t)s0 * HF);
        const float4* p1 = (const float4*)(h + (size_t)s1 * HF);
        short8 a0[4], a1[4];
        #pragma unroll
        for (int f = 0; f < 4; ++f) {
            const int o = f * 8 + q * 2;
            a0[f] = pack_bf16_8(p0[o], p0[o + 1]);
            a1[f] = pack_bf16_8(p1[o], p1[o + 1]);
        }

        floatx4 au0[8], au1[8], aw0[8], aw1[8];
        #pragma unroll
        for (int t = 0; t < 8; ++t) { au0[t] = vzero; au1[t] = vzero; aw0[t] = vzero; aw1[t] = vzero; }

        #pragma unroll
        for (int ks = 0; ks < 4; ++ks) {
            #pragma unroll
            for (int t = 0; t < 8; ++t) {
                const int row = t * 16 + c16;
                const int cu = (ks * 4 + q) ^ swz;          // k in [0,128): W1a
                const int cw = 16 + ((ks * 4 + q) ^ swz);   // k in [128,256): W1b
                const short8 bu = *(const short8*)(&sW[row * K2 + (cu << 3)]);
                const short8 bw = *(const short8*)(&sW[row * K2 + (cw << 3)]);
                au0[t] = __builtin_amdgcn_mfma_f32_16x16x32_bf16(a0[ks], bu, au0[t], 0, 0, 0);
                au1[t] = __builtin_amdgcn_mfma_f32_16x16x32_bf16(a1[ks], bu, au1[t], 0, 0, 0);
                aw0[t] = __builtin_amdgcn_mfma_f32_16x16x32_bf16(a0[ks], bw, aw0[t], 0, 0, 0);
                aw1[t] = __builtin_amdgcn_mfma_f32_16x16x32_bf16(a1[ks], bw, aw1[t], 0, 0, 0);
            }
        }

        // store: D reg r -> node nbase + q*4 + r (subtile 0) / +16 (subtile 1),
        // feature n = t*16 + c16. u gets +b1 folded before bf16 rounding.
        #pragma unroll
        for (int r = 0; r < 4; ++r) {
            const int m0 = nbase + q * 4 + r;
            const int m1 = m0 + 16;
            if (m0 < n_nodes) {
                #pragma unroll
                for (int t = 0; t < 8; ++t) {
                    const int n = t * 16 + c16;
                    uo[(size_t)m0 * HF + n] = (unsigned short)__bfloat16_as_ushort(__float2bfloat16(au0[t][r] + b1f[t]));
                    wo[(size_t)m0 * HF + n] = (unsigned short)__bfloat16_as_ushort(__float2bfloat16(aw0[t][r]));
                }
            }
            if (m1 < n_nodes) {
                #pragma unroll
                for (int t = 0; t < 8; ++t) {
                    const int n = t * 16 + c16;
                    uo[(size_t)m1 * HF + n] = (unsigned short)__bfloat16_as_ushort(__float2bfloat16(au1[t][r] + b1f[t]));
                    wo[(size_t)m1 * HF + n] = (unsigned short)__bfloat16_as_ushort(__float2bfloat16(aw1[t][r]));
                }
            }
        }
    }
}

// =================== R7 edge phase: pure gather + VALU ===================
// 16 lanes per edge; lane j handles features [j*8, j*8+8). 4 edges per
// 16-lane group per iteration (contiguous -> float4 output store).
__global__ __launch_bounds__(256) void edge_score(
    const unsigned short* __restrict__ u,
    const unsigned short* __restrict__ w,
    const int* __restrict__ src,
    const int* __restrict__ dst,
    const float* __restrict__ W2,
    const float* __restrict__ b2,
    float* __restrict__ out,
    const int n_edges)
{
    const int tid  = threadIdx.x;
    const int j    = tid & 15;
    const int grp  = (blockIdx.x * 256 + tid) >> 4;
    const int ngrp = (gridDim.x * 256) >> 4;

    float w2f[8];
    #pragma unroll
    for (int i = 0; i < 8; ++i) w2f[i] = W2[j * 8 + i];
    const float b2f = b2[0];

    for (int base = grp * 4; base < n_edges; base += ngrp * 4) {
        float acc[4];
        BF8 uv[4], wv[4];
        int valid[4];
        #pragma unroll
        for (int k = 0; k < 4; ++k) {
            const int e = base + k;
            valid[k] = e < n_edges;
            const int s = valid[k] ? src[e] : 0;
            const int d = valid[k] ? dst[e] : 0;
            uv[k].v = *(const short8*)(u + (size_t)s * HF + j * 8);
            wv[k].v = *(const short8*)(w + (size_t)d * HF + j * 8);
        }
        #pragma unroll
        for (int k = 0; k < 4; ++k) {
            float a = 0.f;
            #pragma unroll
            for (int i = 0; i < 8; ++i) {
                const float z = bf2f((unsigned short)__bfloat16_as_ushort(uv[k].e[i]))
                              + bf2f((unsigned short)__bfloat16_as_ushort(wv[k].e[i]));
                a += fmaxf(z, 0.f) * w2f[i];
            }
            // reduce over the 16 lanes of this group
            a += __shfl_xor(a, 1);
            a += __shfl_xor(a, 2);
            a += __shfl_xor(a, 4);
            a += __shfl_xor(a, 8);
            acc[k] = a + b2f;
        }
        if (j == 0) {
            if (valid[3]) {
                *(float4*)(out + base) = make_float4(acc[0], acc[1], acc[2], acc[3]);
            } else {
                #pragma unroll
                for (int k = 0; k < 4; ++k) if (valid[k]) out[base + k] = acc[k];
            }
        }
    }
}

// =================== R6 fallback path (kept verbatim) ===================
__global__ __launch_bounds__(256) void cvt_bf16(const float* __restrict__ src,
                                                unsigned short* __restrict__ dst,
                                                int n8) {
    int i = blockIdx.x * 256 + threadIdx.x;
    if (i < n8) {
        const float4* p = (const float4*)src + (size_t)i * 2;
        *(short8*)(dst + (size_t)i * 8) = pack_bf16_8(p[0], p[1]);
    }
}

template <bool HB16>
__global__ __launch_bounds__(256, 2) void mlp_edge(
    const void* __restrict__ hsrc,
    const int* __restrict__ src,
    const int* __restrict__ dst,
    const float* __restrict__ W1,
    const float* __restrict__ b1,
    const float* __restrict__ W2,
    const float* __restrict__ b2,
    float* __restrict__ out,
    const int n_edges,
    const int n_groups)
{
    __shared__ __hip_bfloat16 sW[HF * K2];
    const int tid = threadIdx.x;
    {
        const float4* gw = (const float4*)W1;
        #pragma unroll
        for (int i = 0; i < 16; ++i) {
            const int c = tid + i * 256, row = c >> 5, col = (c & 31) ^ (row & 7);
            *(short8*)(&sW[row * K2 + (col << 3)]) = pack_bf16_8(gw[2 * c], gw[2 * c + 1]);
        }
    }
    __syncthreads();
    const int lane = tid & 63, wave = tid >> 6;
    const int c16 = lane & 15, q = lane >> 4, swz = c16 & 7, gb = lane & 48;
    float b1f[8], w2f[8];
    #pragma unroll
    for (int t = 0; t < 8; ++t) { b1f[t] = b1[t * 16 + c16]; w2f[t] = W2[t * 16 + c16]; }
    const float b2f = b2[0];
    const floatx4 vzero = {0.f, 0.f, 0.f, 0.f};
    for (int g = blockIdx.x; g < n_groups; g += gridDim.x) {
        const int base = g * 128 + wave * 32;
        const int e0 = base + c16, e1 = base + 16 + c16;
        const int s0 = (e0 < n_edges) ? src[e0] : 0;
        const int d0 = (e0 < n_edges) ? dst[e0] : 0;
        const int s1 = (e1 < n_edges) ? src[e1] : 0;
        const int d1 = (e1 < n_edges) ? dst[e1] : 0;
        short8 a0[8], a1[8];
        if (HB16) {
            const unsigned short* hb = (const unsigned short*)hsrc;
            const short8* ps0 = (const short8*)(hb + (size_t)s0 * HF);
            const short8* pd0 = (const short8*)(hb + (size_t)d0 * HF);
            const short8* ps1 = (const short8*)(hb + (size_t)s1 * HF);
            const short8* pd1 = (const short8*)(hb + (size_t)d1 * HF);
            #pragma unroll
            for (int f = 0; f < 4; ++f) {
                a0[f] = ps0[f * 4 + q]; a0[f + 4] = pd0[f * 4 + q];
                a1[f] = ps1[f * 4 + q]; a1[f + 4] = pd1[f * 4 + q];
            }
        } else {
            const float* hf = (const float*)hsrc;
            const float4* ps0 = (const float4*)(hf + (size_t)s0 * HF);
            const float4* pd0 = (const float4*)(hf + (size_t)d0 * HF);
            const float4* ps1 = (const float4*)(hf + (size_t)s1 * HF);
            const float4* pd1 = (const float4*)(hf + (size_t)d1 * HF);
            #pragma unroll
            for (int f = 0; f < 4; ++f) {
                const int o = f * 8 + q * 2;
                a0[f]     = pack_bf16_8(ps0[o], ps0[o + 1]);
                a0[f + 4] = pack_bf16_8(pd0[o], pd0[o + 1]);
                a1[f]     = pack_bf16_8(ps1[o], ps1[o + 1]);
                a1[f + 4] = pack_bf16_8(pd1[o], pd1[o + 1]);
            }
        }
        floatx4 acc0[8], acc1[8];
        #pragma unroll
        for (int t = 0; t < 8; ++t) { acc0[t] = vzero; acc1[t] = vzero; }
        #pragma unroll
        for (int ks = 0; ks < 8; ++ks) {
            #pragma unroll
            for (int t = 0; t < 8; ++t) {
                const int chunk = (ks * 4 + q) ^ swz;
                const short8 bfr = *(const short8*)(&sW[(t * 16 + c16) * K2 + (chunk << 3)]);
                acc0[t] = __builtin_amdgcn_mfma_f32_16x16x32_bf16(a0[ks], bfr, acc0[t], 0, 0, 0);
                acc1[t] = __builtin_amdgcn_mfma_f32_16x16x32_bf16(a1[ks], bfr, acc1[t], 0, 0, 0);
            }
        }
        float p0[4] = {0.f, 0.f, 0.f, 0.f}, p1[4] = {0.f, 0.f, 0.f, 0.f};
        #pragma unroll
        for (int t = 0; t < 8; ++t)
            #pragma unroll
            for (int r = 0; r < 4; ++r) {
                p0[r] += fmaxf(acc0[t][r] + b1f[t], 0.f) * w2f[t];
                p1[r] += fmaxf(acc1[t][r] + b1f[t], 0.f) * w2f[t];
            }
        #pragma unroll
        for (int off = 8; off >= 1; off >>= 1)
            #pragma unroll
            for (int r = 0; r < 4; ++r) {
                p0[r] += __shfl(p0[r], gb | (c16 ^ off));
                p1[r] += __shfl(p1[r], gb | (c16 ^ off));
            }
        if (c16 < 4) {
            const float r0 = (c16 == 0) ? p0[0] : (c16 == 1) ? p0[1] : (c16 == 2) ? p0[2] : p0[3];
            const float r1 = (c16 == 0) ? p1[0] : (c16 == 1) ? p1[1] : (c16 == 2) ? p1[2] : p1[3];
            const int eo0 = base + q * 4 + c16, eo1 = base + 16 + q * 4 + c16;
            if (eo0 < n_edges) out[eo0] = r0 + b2f;
            if (eo1 < n_edges) out[eo1] = r1 + b2f;
        }
    }
}

extern "C" void kernel_launch(void* const* d_in, const int* in_sizes, int n_in,
                              void* d_out, int out_size, void* d_ws, size_t ws_size,
                              hipStream_t stream) {
    const float* h   = (const float*)d_in[0];
    const int*   src = (const int*)d_in[1];
    const int*   dst = (const int*)d_in[2];
    const float* W1  = (const float*)d_in[3];
    const float* b1  = (const float*)d_in[4];
    const float* W2  = (const float*)d_in[5];
    const float* b2  = (const float*)d_in[6];
    float* out = (float*)d_out;

    const int n_edges = in_sizes[1];
    const int n_nodes = in_sizes[0] / HF;
    const size_t uw_bytes = (size_t)n_nodes * HF * 2 * 2;   // u + w bf16

    if (ws_size >= uw_bytes) {
        unsigned short* uo = (unsigned short*)d_ws;
        unsigned short* wo = uo + (size_t)n_nodes * HF;
        const int ngroups = (n_nodes + 127) / 128;
        int pgrid = 256;
        if (pgrid > ngroups) pgrid = ngroups;
        gemm_uw<<<dim3(pgrid), dim3(256), 0, stream>>>(h, W1, b1, uo, wo,
                                                       n_nodes, ngroups);
        edge_score<<<dim3(2048), dim3(256), 0, stream>>>(uo, wo, src, dst,
                                                         W2, b2, out, n_edges);
    } else {
        // fallback: R6 gather-GEMM
        const int n_groups = (n_edges + 127) / 128;
        int grid = 512;
        if (grid > n_groups) grid = n_groups;
        const int    h_elems  = in_sizes[0];
        const size_t hb_bytes = (size_t)h_elems * 2;
        if (ws_size >= hb_bytes && (h_elems & 7) == 0) {
            unsigned short* hb = (unsigned short*)d_ws;
            const int n8 = h_elems / 8;
            cvt_bf16<<<dim3((n8 + 255) / 256), dim3(256), 0, stream>>>(h, hb, n8);
            mlp_edge<true><<<dim3(grid), dim3(256), 0, stream>>>(
                (const void*)hb, src, dst, W1, b1, W2, b2, out, n_edges, n_groups);
        } else {
            mlp_edge<false><<<dim3(grid), dim3(256), 0, stream>>>(
                (const void*)h, src, dst, W1, b1, W2, b2, out, n_edges, n_groups);
        }
    }
}

// Round 9
// 129.537 us; speedup vs baseline: 1.8972x; 1.0352x over previous
//
#include <hip/hip_runtime.h>
#include <hip/hip_bf16.h>

// MLPPredictor: score[e] = W2 . relu(W1 @ concat(h[src],h[dst]) + b1) + b2
// SETTLED (R0-R7): h/W1/b1/W2/b2 = fp32, src/dst = int32, out = fp32.
// R7 split (PASSED full harness incl. post-timing, 134 us): per-node
// u = W1a@h + b1, w = W1b@h (bf16 in ws), then edge phase gathers u[src],
// w[dst], relu-add, dot(W2). R8 (EPG=8 + launch_bounds(256,4) + dual-lane
// stores) passed first validation but diverged post-timing -> REVERTED to the
// R7-proven kernel bodies verbatim. R9 deltas are launch-parameter-only:
//   gemm_uw grid 256->391 (one group per block, same loop code)
//   edge_score grid 2048->9375 (one 4-edge iteration per group, same code)
// MFMA fragment maps (probe-verified on gfx950, R5 mode 0):
//   A: lane holds A[m=lane&15][k=(lane>>4)*8+j]
//   B: lane holds B[k=(lane>>4)*8+j][n=lane&15]
//   D: lane reg r holds D[row=(lane>>4)*4+r][col=lane&15]

typedef __attribute__((ext_vector_type(8))) short short8;   // 8 bf16
typedef __attribute__((ext_vector_type(4))) float floatx4;  // MFMA acc

constexpr int HF = 128;   // H_FEATS
constexpr int K2 = 256;   // 2*H

union BF8 { short8 v; unsigned short s[8]; __hip_bfloat16 e[8]; };

__device__ __forceinline__ short8 pack_bf16_8(float4 a, float4 b) {
    BF8 u;
    u.e[0] = __float2bfloat16(a.x); u.e[1] = __float2bfloat16(a.y);
    u.e[2] = __float2bfloat16(a.z); u.e[3] = __float2bfloat16(a.w);
    u.e[4] = __float2bfloat16(b.x); u.e[5] = __float2bfloat16(b.y);
    u.e[6] = __float2bfloat16(b.z); u.e[7] = __float2bfloat16(b.w);
    return u.v;
}

__device__ __forceinline__ float bf2f(unsigned short s) {
    union { unsigned u; float f; } c; c.u = (unsigned)s << 16; return c.f;
}

// =================== precompute: u/w per-node GEMM (R7 body) ===================
__global__ __launch_bounds__(256, 2) void gemm_uw(
    const float* __restrict__ h,
    const float* __restrict__ W1,
    const float* __restrict__ b1,
    unsigned short* __restrict__ uo,     // [n_nodes][128] bf16 (includes +b1)
    unsigned short* __restrict__ wo,     // [n_nodes][128] bf16
    const int n_nodes,
    const int n_groups)
{
    __shared__ __hip_bfloat16 sW[HF * K2];   // 64 KB, swizzled

    const int tid = threadIdx.x;
    {
        const float4* gw = (const float4*)W1;
        #pragma unroll
        for (int i = 0; i < 16; ++i) {
            const int c = tid + i * 256, row = c >> 5, col = (c & 31) ^ (row & 7);
            *(short8*)(&sW[row * K2 + (col << 3)]) = pack_bf16_8(gw[2 * c], gw[2 * c + 1]);
        }
    }
    __syncthreads();

    const int lane = tid & 63;
    const int wave = tid >> 6;
    const int c16  = lane & 15;
    const int q    = lane >> 4;
    const int swz  = c16 & 7;

    float b1f[8];
    #pragma unroll
    for (int t = 0; t < 8; ++t) b1f[t] = b1[t * 16 + c16];

    const floatx4 vzero = {0.f, 0.f, 0.f, 0.f};

    for (int g = blockIdx.x; g < n_groups; g += gridDim.x) {
        const int nbase = g * 128 + wave * 32;
        const int n0 = nbase + c16;          // subtile-0 A-row node
        const int n1 = nbase + 16 + c16;     // subtile-1 A-row node
        const int s0 = (n0 < n_nodes) ? n0 : 0;
        const int s1 = (n1 < n_nodes) ? n1 : 0;

        const float4* p0 = (const float4*)(h + (size_t)s0 * HF);
        const float4* p1 = (const float4*)(h + (size_t)s1 * HF);
        short8 a0[4], a1[4];
        #pragma unroll
        for (int f = 0; f < 4; ++f) {
            const int o = f * 8 + q * 2;
            a0[f] = pack_bf16_8(p0[o], p0[o + 1]);
            a1[f] = pack_bf16_8(p1[o], p1[o + 1]);
        }

        floatx4 au0[8], au1[8], aw0[8], aw1[8];
        #pragma unroll
        for (int t = 0; t < 8; ++t) { au0[t] = vzero; au1[t] = vzero; aw0[t] = vzero; aw1[t] = vzero; }

        #pragma unroll
        for (int ks = 0; ks < 4; ++ks) {
            #pragma unroll
            for (int t = 0; t < 8; ++t) {
                const int row = t * 16 + c16;
                const int cu = (ks * 4 + q) ^ swz;          // k in [0,128): W1a
                const int cw = 16 + ((ks * 4 + q) ^ swz);   // k in [128,256): W1b
                const short8 bu = *(const short8*)(&sW[row * K2 + (cu << 3)]);
                const short8 bw = *(const short8*)(&sW[row * K2 + (cw << 3)]);
                au0[t] = __builtin_amdgcn_mfma_f32_16x16x32_bf16(a0[ks], bu, au0[t], 0, 0, 0);
                au1[t] = __builtin_amdgcn_mfma_f32_16x16x32_bf16(a1[ks], bu, au1[t], 0, 0, 0);
                aw0[t] = __builtin_amdgcn_mfma_f32_16x16x32_bf16(a0[ks], bw, aw0[t], 0, 0, 0);
                aw1[t] = __builtin_amdgcn_mfma_f32_16x16x32_bf16(a1[ks], bw, aw1[t], 0, 0, 0);
            }
        }

        #pragma unroll
        for (int r = 0; r < 4; ++r) {
            const int m0 = nbase + q * 4 + r;
            const int m1 = m0 + 16;
            if (m0 < n_nodes) {
                #pragma unroll
                for (int t = 0; t < 8; ++t) {
                    const int n = t * 16 + c16;
                    uo[(size_t)m0 * HF + n] = (unsigned short)__bfloat16_as_ushort(__float2bfloat16(au0[t][r] + b1f[t]));
                    wo[(size_t)m0 * HF + n] = (unsigned short)__bfloat16_as_ushort(__float2bfloat16(aw0[t][r]));
                }
            }
            if (m1 < n_nodes) {
                #pragma unroll
                for (int t = 0; t < 8; ++t) {
                    const int n = t * 16 + c16;
                    uo[(size_t)m1 * HF + n] = (unsigned short)__bfloat16_as_ushort(__float2bfloat16(au1[t][r] + b1f[t]));
                    wo[(size_t)m1 * HF + n] = (unsigned short)__bfloat16_as_ushort(__float2bfloat16(aw1[t][r]));
                }
            }
        }
    }
}

// =================== edge phase: pure gather + VALU (R7 body) ===================
// 16 lanes per edge-group; lane j handles features [j*8, j*8+8). 4 edges per
// group per iteration (contiguous -> float4 output store by lane 0).
__global__ __launch_bounds__(256) void edge_score(
    const unsigned short* __restrict__ u,
    const unsigned short* __restrict__ w,
    const int* __restrict__ src,
    const int* __restrict__ dst,
    const float* __restrict__ W2,
    const float* __restrict__ b2,
    float* __restrict__ out,
    const int n_edges)
{
    const int tid  = threadIdx.x;
    const int j    = tid & 15;
    const int grp  = (blockIdx.x * 256 + tid) >> 4;
    const int ngrp = (gridDim.x * 256) >> 4;

    float w2f[8];
    #pragma unroll
    for (int i = 0; i < 8; ++i) w2f[i] = W2[j * 8 + i];
    const float b2f = b2[0];

    for (int base = grp * 4; base < n_edges; base += ngrp * 4) {
        float acc[4];
        BF8 uv[4], wv[4];
        int valid[4];
        #pragma unroll
        for (int k = 0; k < 4; ++k) {
            const int e = base + k;
            valid[k] = e < n_edges;
            const int s = valid[k] ? src[e] : 0;
            const int d = valid[k] ? dst[e] : 0;
            uv[k].v = *(const short8*)(u + (size_t)s * HF + j * 8);
            wv[k].v = *(const short8*)(w + (size_t)d * HF + j * 8);
        }
        #pragma unroll
        for (int k = 0; k < 4; ++k) {
            float a = 0.f;
            #pragma unroll
            for (int i = 0; i < 8; ++i) {
                const float z = bf2f(uv[k].s[i]) + bf2f(wv[k].s[i]);
                a += fmaxf(z, 0.f) * w2f[i];
            }
            a += __shfl_xor(a, 1);
            a += __shfl_xor(a, 2);
            a += __shfl_xor(a, 4);
            a += __shfl_xor(a, 8);
            acc[k] = a + b2f;
        }
        if (j == 0) {
            if (valid[3]) {
                *(float4*)(out + base) = make_float4(acc[0], acc[1], acc[2], acc[3]);
            } else {
                #pragma unroll
                for (int k = 0; k < 4; ++k) if (valid[k]) out[base + k] = acc[k];
            }
        }
    }
}

// =================== R6 fallback path (ws too small; kept) ===================
__global__ __launch_bounds__(256) void cvt_bf16(const float* __restrict__ src,
                                                unsigned short* __restrict__ dst,
                                                int n8) {
    int i = blockIdx.x * 256 + threadIdx.x;
    if (i < n8) {
        const float4* p = (const float4*)src + (size_t)i * 2;
        *(short8*)(dst + (size_t)i * 8) = pack_bf16_8(p[0], p[1]);
    }
}

template <bool HB16>
__global__ __launch_bounds__(256, 2) void mlp_edge(
    const void* __restrict__ hsrc,
    const int* __restrict__ src,
    const int* __restrict__ dst,
    const float* __restrict__ W1,
    const float* __restrict__ b1,
    const float* __restrict__ W2,
    const float* __restrict__ b2,
    float* __restrict__ out,
    const int n_edges,
    const int n_groups)
{
    __shared__ __hip_bfloat16 sW[HF * K2];
    const int tid = threadIdx.x;
    {
        const float4* gw = (const float4*)W1;
        #pragma unroll
        for (int i = 0; i < 16; ++i) {
            const int c = tid + i * 256, row = c >> 5, col = (c & 31) ^ (row & 7);
            *(short8*)(&sW[row * K2 + (col << 3)]) = pack_bf16_8(gw[2 * c], gw[2 * c + 1]);
        }
    }
    __syncthreads();
    const int lane = tid & 63, wave = tid >> 6;
    const int c16 = lane & 15, q = lane >> 4, swz = c16 & 7, gb = lane & 48;
    float b1f[8], w2f[8];
    #pragma unroll
    for (int t = 0; t < 8; ++t) { b1f[t] = b1[t * 16 + c16]; w2f[t] = W2[t * 16 + c16]; }
    const float b2f = b2[0];
    const floatx4 vzero = {0.f, 0.f, 0.f, 0.f};
    for (int g = blockIdx.x; g < n_groups; g += gridDim.x) {
        const int base = g * 128 + wave * 32;
        const int e0 = base + c16, e1 = base + 16 + c16;
        const int s0 = (e0 < n_edges) ? src[e0] : 0;
        const int d0 = (e0 < n_edges) ? dst[e0] : 0;
        const int s1 = (e1 < n_edges) ? src[e1] : 0;
        const int d1 = (e1 < n_edges) ? dst[e1] : 0;
        short8 a0[8], a1[8];
        if (HB16) {
            const unsigned short* hb = (const unsigned short*)hsrc;
            const short8* ps0 = (const short8*)(hb + (size_t)s0 * HF);
            const short8* pd0 = (const short8*)(hb + (size_t)d0 * HF);
            const short8* ps1 = (const short8*)(hb + (size_t)s1 * HF);
            const short8* pd1 = (const short8*)(hb + (size_t)d1 * HF);
            #pragma unroll
            for (int f = 0; f < 4; ++f) {
                a0[f] = ps0[f * 4 + q]; a0[f + 4] = pd0[f * 4 + q];
                a1[f] = ps1[f * 4 + q]; a1[f + 4] = pd1[f * 4 + q];
            }
        } else {
            const float* hf = (const float*)hsrc;
            const float4* ps0 = (const float4*)(hf + (size_t)s0 * HF);
            const float4* pd0 = (const float4*)(hf + (size_t)d0 * HF);
            const float4* ps1 = (const float4*)(hf + (size_t)s1 * HF);
            const float4* pd1 = (const float4*)(hf + (size_t)d1 * HF);
            #pragma unroll
            for (int f = 0; f < 4; ++f) {
                const int o = f * 8 + q * 2;
                a0[f]     = pack_bf16_8(ps0[o], ps0[o + 1]);
                a0[f + 4] = pack_bf16_8(pd0[o], pd0[o + 1]);
                a1[f]     = pack_bf16_8(ps1[o], ps1[o + 1]);
                a1[f + 4] = pack_bf16_8(pd1[o], pd1[o + 1]);
            }
        }
        floatx4 acc0[8], acc1[8];
        #pragma unroll
        for (int t = 0; t < 8; ++t) { acc0[t] = vzero; acc1[t] = vzero; }
        #pragma unroll
        for (int ks = 0; ks < 8; ++ks) {
            #pragma unroll
            for (int t = 0; t < 8; ++t) {
                const int chunk = (ks * 4 + q) ^ swz;
                const short8 bfr = *(const short8*)(&sW[(t * 16 + c16) * K2 + (chunk << 3)]);
                acc0[t] = __builtin_amdgcn_mfma_f32_16x16x32_bf16(a0[ks], bfr, acc0[t], 0, 0, 0);
                acc1[t] = __builtin_amdgcn_mfma_f32_16x16x32_bf16(a1[ks], bfr, acc1[t], 0, 0, 0);
            }
        }
        float p0[4] = {0.f, 0.f, 0.f, 0.f}, p1[4] = {0.f, 0.f, 0.f, 0.f};
        #pragma unroll
        for (int t = 0; t < 8; ++t)
            #pragma unroll
            for (int r = 0; r < 4; ++r) {
                p0[r] += fmaxf(acc0[t][r] + b1f[t], 0.f) * w2f[t];
                p1[r] += fmaxf(acc1[t][r] + b1f[t], 0.f) * w2f[t];
            }
        #pragma unroll
        for (int off = 8; off >= 1; off >>= 1)
            #pragma unroll
            for (int r = 0; r < 4; ++r) {
                p0[r] += __shfl(p0[r], gb | (c16 ^ off));
                p1[r] += __shfl(p1[r], gb | (c16 ^ off));
            }
        if (c16 < 4) {
            const float r0 = (c16 == 0) ? p0[0] : (c16 == 1) ? p0[1] : (c16 == 2) ? p0[2] : p0[3];
            const float r1 = (c16 == 0) ? p1[0] : (c16 == 1) ? p1[1] : (c16 == 2) ? p1[2] : p1[3];
            const int eo0 = base + q * 4 + c16, eo1 = base + 16 + q * 4 + c16;
            if (eo0 < n_edges) out[eo0] = r0 + b2f;
            if (eo1 < n_edges) out[eo1] = r1 + b2f;
        }
    }
}

extern "C" void kernel_launch(void* const* d_in, const int* in_sizes, int n_in,
                              void* d_out, int out_size, void* d_ws, size_t ws_size,
                              hipStream_t stream) {
    const float* h   = (const float*)d_in[0];
    const int*   src = (const int*)d_in[1];
    const int*   dst = (const int*)d_in[2];
    const float* W1  = (const float*)d_in[3];
    const float* b1  = (const float*)d_in[4];
    const float* W2  = (const float*)d_in[5];
    const float* b2  = (const float*)d_in[6];
    float* out = (float*)d_out;

    const int n_edges = in_sizes[1];
    const int n_nodes = in_sizes[0] / HF;
    const size_t uw_bytes = (size_t)n_nodes * HF * 2 * 2;   // u + w bf16

    if (ws_size >= uw_bytes) {
        unsigned short* uo = (unsigned short*)d_ws;
        unsigned short* wo = uo + (size_t)n_nodes * HF;
        const int ngroups = (n_nodes + 127) / 128;          // 391
        // R9 delta 1: grid == ngroups (one group per block; same loop code)
        gemm_uw<<<dim3(ngroups), dim3(256), 0, stream>>>(h, W1, b1, uo, wo,
                                                         n_nodes, ngroups);
        // R9 delta 2: one 4-edge iteration per 16-lane group
        const int egrid = (n_edges + 63) / 64;              // 9375
        edge_score<<<dim3(egrid), dim3(256), 0, stream>>>(uo, wo, src, dst,
                                                          W2, b2, out, n_edges);
    } else {
        const int n_groups = (n_edges + 127) / 128;
        int grid = 512;
        if (grid > n_groups) grid = n_groups;
        const int    h_elems  = in_sizes[0];
        const size_t hb_bytes = (size_t)h_elems * 2;
        if (ws_size >= hb_bytes && (h_elems & 7) == 0) {
            unsigned short* hb = (unsigned short*)d_ws;
            const int n8 = h_elems / 8;
            cvt_bf16<<<dim3((n8 + 255) / 256), dim3(256), 0, stream>>>(h, hb, n8);
            mlp_edge<true><<<dim3(grid), dim3(256), 0, stream>>>(
                (const void*)hb, src, dst, W1, b1, W2, b2, out, n_edges, n_groups);
        } else {
            mlp_edge<false><<<dim3(grid), dim3(256), 0, stream>>>(
                (const void*)h, src, dst, W1, b1, W2, b2, out, n_edges, n_groups);
        }
    }
}